// Round 6
// baseline (628.057 us; speedup 1.0000x reference)
//
#include <hip/hip_runtime.h>
#include <math.h>

#define N_NODES 50000
#define N_EDGES 800000
#define NFEAT 512
#define NHID 64
#define NHEAD 8
#define NCLASS 40
#define NEG_SLOPE 0.2f

#define N_RT 3125           // 50000/16 row tiles
#define N_RT_PAD 3128       // padded to multiple of 8 (gemm1 block = 8 rowtiles)
#define SCAN_NBLK 49        // ceil(50000/1024)
#define CASTX_NBLK 12512    // N_RT_PAD*1024/256
#define PACK_NBLK (CASTX_NBLK + 140)

typedef __attribute__((ext_vector_type(8))) short short8;
typedef __attribute__((ext_vector_type(4))) short short4v;
typedef __attribute__((ext_vector_type(4))) float f32x4;

__device__ __forceinline__ float bf2f(short s) {
    return __uint_as_float(((unsigned)(unsigned short)s) << 16);
}
__device__ __forceinline__ short f2bf(float f) {
    unsigned u = __float_as_uint(f);
    unsigned r = (u + 0x7FFFu + ((u >> 16) & 1u)) >> 16;
    return (short)(unsigned short)r;
}

// h1 row permutation: slot c' = head*64 + f', f' = (l&15)*4 + ct', head = 2g+(ct>=4)
// orig  c = g*128 + ct*16 + (l&15)   [g = colgroup, ct = coltile, within gemm1]

// ---------------- CSR build ----------------

__global__ void count_deg(const int* __restrict__ el, int* __restrict__ deg) {
    int e = blockIdx.x * blockDim.x + threadIdx.x;
    if (e < N_EDGES) atomicAdd(&deg[el[N_EDGES + e]], 1);
}

__global__ __launch_bounds__(256) void scan1(const int* __restrict__ deg,
                                             int* __restrict__ loc,
                                             int* __restrict__ bsum) {
    int tid = threadIdx.x, lane = tid & 63, w = tid >> 6;
    int base = blockIdx.x * 1024 + tid * 4;
    int d0 = (base + 0 < N_NODES) ? deg[base + 0] : 0;
    int d1 = (base + 1 < N_NODES) ? deg[base + 1] : 0;
    int d2 = (base + 2 < N_NODES) ? deg[base + 2] : 0;
    int d3 = (base + 3 < N_NODES) ? deg[base + 3] : 0;
    int s0 = d0, s1 = s0 + d1, s2 = s1 + d2, s3 = s2 + d3;
    int t = s3;
#pragma unroll
    for (int d = 1; d < 64; d <<= 1) {
        int u = __shfl_up(t, d);
        if (lane >= d) t += u;
    }
    __shared__ int wsum[4];
    if (lane == 63) wsum[w] = t;
    __syncthreads();
    int woff = 0;
#pragma unroll
    for (int j = 0; j < 4; ++j) woff += (j < w) ? wsum[j] : 0;
    int excl = woff + t - s3;
    if (base + 0 < N_NODES) loc[base + 0] = excl + s0;
    if (base + 1 < N_NODES) loc[base + 1] = excl + s1;
    if (base + 2 < N_NODES) loc[base + 2] = excl + s2;
    if (base + 3 < N_NODES) loc[base + 3] = excl + s3;
    if (tid == 255) bsum[blockIdx.x] = woff + t;
}

__global__ void scan2(const int* __restrict__ bsum, int* __restrict__ boff) {
    int lane = threadIdx.x;
    int v = (lane < SCAN_NBLK) ? bsum[lane] : 0;
    int t = v;
#pragma unroll
    for (int d = 1; d < 64; d <<= 1) {
        int u = __shfl_up(t, d);
        if (lane >= d) t += u;
    }
    if (lane < SCAN_NBLK) boff[lane] = t - v;
}

__global__ __launch_bounds__(256) void scan3(const int* __restrict__ deg,
                                             const int* __restrict__ loc,
                                             const int* __restrict__ boff,
                                             int* __restrict__ ptr,
                                             int* __restrict__ cursor) {
    int base = blockIdx.x * 1024 + threadIdx.x * 4;
    int off = boff[blockIdx.x];
    if (blockIdx.x == 0 && threadIdx.x == 0) ptr[0] = 0;
#pragma unroll
    for (int k = 0; k < 4; ++k) {
        int i = base + k;
        if (i < N_NODES) {
            int P = off + loc[i];
            ptr[i + 1] = P;
            cursor[i] = P - deg[i];
        }
    }
}

__global__ void scatter_k(const int* __restrict__ el, int* __restrict__ cursor,
                          int* __restrict__ esrc) {
    int e = blockIdx.x * blockDim.x + threadIdx.x;
    if (e >= N_EDGES) return;
    int dst = el[N_EDGES + e];
    int p = atomicAdd(&cursor[dst], 1);
    esrc[p] = el[e];
}

// ---------------- pack: cast x -> A-frag bf16  AND  repack W1/W2 -> B-frag bf16 ----------------
__global__ __launch_bounds__(256) void pack_k(const float* __restrict__ x,
                                              const float* __restrict__ W1,
                                              const float* __restrict__ W2,
                                              short* __restrict__ xp,
                                              short* __restrict__ Wp1,
                                              short* __restrict__ Wp2) {
    if (blockIdx.x < CASTX_NBLK) {
        int t = blockIdx.x * 256 + threadIdx.x;       // < N_RT_PAD*1024
        int l = t & 63, ks = (t >> 6) & 15, rt = t >> 10;
        short8 o;
        if (rt >= N_RT) {
#pragma unroll
            for (int j = 0; j < 8; ++j) o[j] = 0;
        } else {
            int row = rt * 16 + (l & 15);
            int col = ks * 32 + (l >> 4) * 8;
            const float* p = x + (size_t)row * NFEAT + col;
            float4 v0 = *(const float4*)p;
            float4 v1 = *(const float4*)(p + 4);
            o[0] = f2bf(v0.x); o[1] = f2bf(v0.y); o[2] = f2bf(v0.z); o[3] = f2bf(v0.w);
            o[4] = f2bf(v1.x); o[5] = f2bf(v1.y); o[6] = f2bf(v1.z); o[7] = f2bf(v1.w);
        }
        *(short8*)(xp + (size_t)t * 8) = o;
        return;
    }
    int t = (blockIdx.x - CASTX_NBLK) * 256 + threadIdx.x;
    if (t < 32768) {
        // Wp1: B-frag, orig column order (gemm1 epilogue handles the h1 permutation)
        int l = t & 63, ct = (t >> 6) & 7, ks = (t >> 9) & 15, g = t >> 13;
        int c = g * 128 + ct * 16 + (l & 15);
        int head = c >> 6, f = c & 63;
        int k0 = ks * 32 + (l >> 4) * 8;
        short8 o;
#pragma unroll
        for (int j = 0; j < 8; ++j)
            o[j] = f2bf(W1[(size_t)head * NFEAT * NHID + (k0 + j) * NHID + f]);
        *(short8*)(Wp1 + (size_t)t * 8) = o;
    } else if (t < 32768 + 3072) {
        // Wp2: K dimension follows the h1/hcat permutation
        int u = t - 32768;
        int l = u & 63;
        int kc = u >> 6;                 // ks*3+ct
        int ct2 = kc % 3, ks = kc / 3;
        int col = ct2 * 16 + (l & 15);
        short8 o;
#pragma unroll
        for (int j = 0; j < 8; ++j) {
            int kp = ks * 32 + (l >> 4) * 8 + j;      // permuted K slot
            int head = kp >> 6, fp = kp & 63;
            int l15 = fp >> 2, ctp = fp & 3;
            int ct = ((head & 1) << 2) | ctp;
            int gg = head >> 1;
            int orig_k = gg * 128 + ct * 16 + l15;
            o[j] = (col < NCLASS) ? f2bf(W2[(size_t)orig_k * NCLASS + col]) : (short)0;
        }
        *(short8*)(Wp2 + (size_t)u * 8) = o;
    }
}

// ---------------- gemm1: MFMA, no LDS + fused s1 scores, permuted coalesced h1 stores ----------------
__global__ __launch_bounds__(256) void gemm1(const short* __restrict__ xp,
                                             const short* __restrict__ Wp1,
                                             const float* __restrict__ a1,
                                             short* __restrict__ h1p,
                                             float* __restrict__ s1s,
                                             float* __restrict__ s1d) {
    int w = threadIdx.x >> 6, l = threadIdx.x & 63;
    int g = blockIdx.x;
    int rt0 = blockIdx.y * 8 + w * 2;
    f32x4 acc[2][8];
#pragma unroll
    for (int i = 0; i < 2; ++i)
#pragma unroll
        for (int ct = 0; ct < 8; ++ct) acc[i][ct] = (f32x4){0.f, 0.f, 0.f, 0.f};

#pragma unroll 2
    for (int ks = 0; ks < 16; ++ks) {
        short8 a0 = *(const short8*)(xp + ((size_t)(rt0 * 16 + ks) * 64 + l) * 8);
        short8 a1v = *(const short8*)(xp + ((size_t)((rt0 + 1) * 16 + ks) * 64 + l) * 8);
        const short* bp = Wp1 + (size_t)(g * 16 + ks) * 4096 + l * 8;
#pragma unroll
        for (int ct = 0; ct < 8; ++ct) {
            short8 b = *(const short8*)(bp + ct * 512);
            acc[0][ct] = __builtin_amdgcn_mfma_f32_16x16x32_bf16(a0, b, acc[0][ct], 0, 0, 0);
            acc[1][ct] = __builtin_amdgcn_mfma_f32_16x16x32_bf16(a1v, b, acc[1][ct], 0, 0, 0);
        }
    }
    float avs[8], avd[8];
#pragma unroll
    for (int ct = 0; ct < 8; ++ct) {
        int head = 2 * g + (ct >> 2);
        int f = (ct & 3) * 16 + (l & 15);
        avs[ct] = a1[head * 128 + f];
        avd[ct] = a1[head * 128 + 64 + f];
    }
    int l15 = l & 15;
    int rbase = (l >> 4) * 4;
#pragma unroll
    for (int i = 0; i < 2; ++i)
#pragma unroll
        for (int r = 0; r < 4; ++r) {
            int row = (rt0 + i) * 16 + rbase + r;
            float ps0 = 0.f, pd0 = 0.f, ps1 = 0.f, pd1 = 0.f;
#pragma unroll
            for (int ct = 0; ct < 4; ++ct) {
                ps0 += acc[i][ct][r] * avs[ct];
                pd0 += acc[i][ct][r] * avd[ct];
            }
#pragma unroll
            for (int ct = 4; ct < 8; ++ct) {
                ps1 += acc[i][ct][r] * avs[ct];
                pd1 += acc[i][ct][r] * avd[ct];
            }
#pragma unroll
            for (int mask = 1; mask < 16; mask <<= 1) {
                ps0 += __shfl_xor(ps0, mask);
                pd0 += __shfl_xor(pd0, mask);
                ps1 += __shfl_xor(ps1, mask);
                pd1 += __shfl_xor(pd1, mask);
            }
            if (row < N_NODES) {
                if (l15 == 0) {
                    s1s[row * 8 + 2 * g]     = ps0;
                    s1d[row * 8 + 2 * g]     = pd0;
                    s1s[row * 8 + 2 * g + 1] = ps1;
                    s1d[row * 8 + 2 * g + 1] = pd1;
                }
                // permuted coalesced stores: head0 = 2g slots [g*128 + l15*4 .. +3], head1 at +64
                short4v o0, o1;
#pragma unroll
                for (int c = 0; c < 4; ++c) { o0[c] = f2bf(acc[i][c][r]); o1[c] = f2bf(acc[i][4 + c][r]); }
                size_t base = (size_t)row * 512 + g * 128 + l15 * 4;
                *(short4v*)(h1p + base) = o0;
                *(short4v*)(h1p + base + 64) = o1;
            }
        }
}

// ---------------- fused layer-1 attention: wave per dst, ALL heads, unroll-2 prefetch ----------------
__global__ __launch_bounds__(256) void att1(const int* __restrict__ ptr,
                                            const int* __restrict__ esrc,
                                            const float* __restrict__ s1s,
                                            const float* __restrict__ s1d,
                                            const short* __restrict__ h1p,
                                            const float* __restrict__ b1,
                                            short* __restrict__ hcatp) {
    int n = blockIdx.x * 4 + (threadIdx.x >> 6);
    int l = threadIdx.x & 63;
    if (n >= N_NODES) return;
    int beg = ptr[n], end = ptr[n + 1];
    int h = l >> 3;                           // permuted: head = l>>3 (slots c' = l*8+j)
    float sd = s1d[n * 8 + h];
    float den = 0.f;
    float acc[8] = {0.f, 0.f, 0.f, 0.f, 0.f, 0.f, 0.f, 0.f};
    if (beg < end) {
        int sA = esrc[beg];
        int sB = (beg + 1 < end) ? esrc[beg + 1] : sA;
        short8 rA = *(const short8*)(h1p + (size_t)sA * 512 + l * 8);
        short8 rB = *(const short8*)(h1p + (size_t)sB * 512 + l * 8);
        float tA = s1s[sA * 8 + h];
        float tB = s1s[sB * 8 + h];
        int i = beg;
        while (i + 2 < end) {
            int nA = esrc[i + 2];
            int nB = (i + 3 < end) ? esrc[i + 3] : nA;
            short8 prA = *(const short8*)(h1p + (size_t)nA * 512 + l * 8);
            short8 prB = *(const short8*)(h1p + (size_t)nB * 512 + l * 8);
            float ptA = s1s[nA * 8 + h];
            float ptB = s1s[nB * 8 + h];
            float scA = tA + sd; scA = fmaxf(scA, NEG_SLOPE * scA);
            float scB = tB + sd; scB = fmaxf(scB, NEG_SLOPE * scB);
            float wA = __expf(scA), wB = __expf(scB);
            den += wA + wB;
#pragma unroll
            for (int j = 0; j < 8; ++j) acc[j] += wA * bf2f(rA[j]) + wB * bf2f(rB[j]);
            rA = prA; rB = prB; tA = ptA; tB = ptB;
            i += 2;
        }
        float scA = tA + sd; scA = fmaxf(scA, NEG_SLOPE * scA);
        float wA = __expf(scA);
        den += wA;
#pragma unroll
        for (int j = 0; j < 8; ++j) acc[j] += wA * bf2f(rA[j]);
        if (i + 1 < end) {
            float scB = tB + sd; scB = fmaxf(scB, NEG_SLOPE * scB);
            float wB = __expf(scB);
            den += wB;
#pragma unroll
            for (int j = 0; j < 8; ++j) acc[j] += wB * bf2f(rB[j]);
        }
    }
    float rden = 1.f / fmaxf(den, 1e-16f);
    short8 o;
#pragma unroll
    for (int j = 0; j < 8; ++j) {
        // permuted slot c' = l*8+j  ->  orig b1 index = head*64 + (j&3)*16 + (l&7)*2 + (j>>2)
        int forig = (j & 3) * 16 + (l & 7) * 2 + (j >> 2);
        float v = acc[j] * rden + b1[h * 64 + forig];
        v = v > 0.f ? v : (__expf(v) - 1.f);    // ELU
        o[j] = f2bf(v);
    }
    size_t addr = (((size_t)(n >> 4) * 16 + (l >> 2)) * 64 + (l & 3) * 16 + (n & 15)) * 8;
    *(short8*)(hcatp + addr) = o;
}

// ---------------- gemm2: MFMA + fused s2 scores. wave per rowtile ----------------
__global__ __launch_bounds__(256) void gemm2(const short* __restrict__ hcatp,
                                             const short* __restrict__ Wp2,
                                             const float* __restrict__ a2,
                                             short* __restrict__ h2,
                                             float* __restrict__ s2s,
                                             float* __restrict__ s2d) {
    int w = threadIdx.x >> 6, l = threadIdx.x & 63;
    int rt = blockIdx.x * 4 + w;                  // < N_RT_PAD
    f32x4 acc[3];
#pragma unroll
    for (int ct = 0; ct < 3; ++ct) acc[ct] = (f32x4){0.f, 0.f, 0.f, 0.f};
#pragma unroll 2
    for (int ks = 0; ks < 16; ++ks) {
        short8 a = *(const short8*)(hcatp + ((size_t)(rt * 16 + ks) * 64 + l) * 8);
        const short* bp = Wp2 + (size_t)(ks * 3) * 512 + l * 8;
#pragma unroll
        for (int ct = 0; ct < 3; ++ct) {
            short8 b = *(const short8*)(bp + ct * 512);
            acc[ct] = __builtin_amdgcn_mfma_f32_16x16x32_bf16(a, b, acc[ct], 0, 0, 0);
        }
    }
    float ps[4] = {0.f, 0.f, 0.f, 0.f}, pd[4] = {0.f, 0.f, 0.f, 0.f};
    int cl = l & 15, rb = (l >> 4) * 4;
#pragma unroll
    for (int ct = 0; ct < 3; ++ct) {
        int col = ct * 16 + cl;
        if (col < NCLASS) {
#pragma unroll
            for (int r = 0; r < 4; ++r) {
                ps[r] += acc[ct][r] * a2[col];
                pd[r] += acc[ct][r] * a2[NCLASS + col];
                int row = rt * 16 + rb + r;
                if (row < N_NODES) h2[(size_t)row * NCLASS + col] = f2bf(acc[ct][r]);
            }
        }
    }
#pragma unroll
    for (int mask = 1; mask < 16; mask <<= 1)
#pragma unroll
        for (int r = 0; r < 4; ++r) {
            ps[r] += __shfl_xor(ps[r], mask);
            pd[r] += __shfl_xor(pd[r], mask);
        }
    if (cl == 0) {
#pragma unroll
        for (int r = 0; r < 4; ++r) {
            int row = rt * 16 + rb + r;
            if (row < N_NODES) { s2s[row] = ps[r]; s2d[row] = pd[r]; }
        }
    }
}

// ---------------- fused layer-2 attention + log_softmax: wave per dst, unroll-2 ----------------
__global__ __launch_bounds__(256) void att2(const int* __restrict__ ptr,
                                            const int* __restrict__ esrc,
                                            const float* __restrict__ s2s,
                                            const float* __restrict__ s2d,
                                            const short* __restrict__ h2,
                                            const float* __restrict__ b2,
                                            float* __restrict__ out) {
    int n = blockIdx.x * 4 + (threadIdx.x >> 6);
    int l = threadIdx.x & 63;
    if (n >= N_NODES) return;
    int beg = ptr[n], end = ptr[n + 1];
    float sd = s2d[n];
    float den = 0.f, acc = 0.f;
    if (beg < end) {
        int sA = esrc[beg];
        int sB = (beg + 1 < end) ? esrc[beg + 1] : sA;
        float rA = (l < NCLASS) ? bf2f(h2[(size_t)sA * NCLASS + l]) : 0.f;
        float rB = (l < NCLASS) ? bf2f(h2[(size_t)sB * NCLASS + l]) : 0.f;
        float tA = s2s[sA], tB = s2s[sB];
        int i = beg;
        while (i + 2 < end) {
            int nA = esrc[i + 2];
            int nB = (i + 3 < end) ? esrc[i + 3] : nA;
            float prA = (l < NCLASS) ? bf2f(h2[(size_t)nA * NCLASS + l]) : 0.f;
            float prB = (l < NCLASS) ? bf2f(h2[(size_t)nB * NCLASS + l]) : 0.f;
            float ptA = s2s[nA], ptB = s2s[nB];
            float scA = tA + sd; scA = fmaxf(scA, NEG_SLOPE * scA);
            float scB = tB + sd; scB = fmaxf(scB, NEG_SLOPE * scB);
            float wA = __expf(scA), wB = __expf(scB);
            den += wA + wB;
            acc += wA * rA + wB * rB;
            rA = prA; rB = prB; tA = ptA; tB = ptB;
            i += 2;
        }
        float scA = tA + sd; scA = fmaxf(scA, NEG_SLOPE * scA);
        float wA = __expf(scA);
        den += wA; acc += wA * rA;
        if (i + 1 < end) {
            float scB = tB + sd; scB = fmaxf(scB, NEG_SLOPE * scB);
            float wB = __expf(scB);
            den += wB; acc += wB * rB;
        }
    }
    float v = (l < NCLASS) ? acc / fmaxf(den, 1e-16f) + b2[l] : -INFINITY;
    float mx = v;
#pragma unroll
    for (int o = 32; o; o >>= 1) mx = fmaxf(mx, __shfl_down(mx, o));
    mx = __shfl(mx, 0);
    float ex = (l < NCLASS) ? __expf(v - mx) : 0.f;
    float s = ex;
#pragma unroll
    for (int o = 32; o; o >>= 1) s += __shfl_down(s, o);
    s = __shfl(s, 0);
    float ls = __logf(s);
    if (l < NCLASS) out[(size_t)n * NCLASS + l] = v - mx - ls;
}

// ---------------- launch ----------------

extern "C" void kernel_launch(void* const* d_in, const int* in_sizes, int n_in,
                              void* d_out, int out_size, void* d_ws, size_t ws_size,
                              hipStream_t stream) {
    const float* x  = (const float*)d_in[0];
    const int*   el = (const int*)d_in[1];
    const float* W1 = (const float*)d_in[2];
    const float* a1 = (const float*)d_in[3];
    const float* b1 = (const float*)d_in[4];
    const float* W2 = (const float*)d_in[5];
    const float* a2 = (const float*)d_in[6];
    const float* b2 = (const float*)d_in[7];
    float* out = (float*)d_out;

    short* sbase = (short*)d_ws;
    short* xp    = sbase;                          // 25,624,576
    short* hcatp = sbase + 25624576;               // 25,624,576
    short* h1p   = sbase + 51249152;               // 25,600,000
    short* Wp1   = sbase + 76849152;               //    262,144
    short* Wp2   = sbase + 77111296;               //     24,576
    short* h2    = sbase + 77135872;               //  2,000,000
    float* fbase = (float*)(sbase + 79135872);
    float* s1s   = fbase;                          //    400,000
    float* s1d   = fbase + 400000;                 //    400,000
    float* s2s   = fbase + 800000;                 //     50,000
    float* s2d   = fbase + 850000;                 //     50,000
    int*   ibase = (int*)(fbase + 900000);
    int*   deg    = ibase;                         //     50,000
    int*   ptr    = ibase + 50000;                 //     50,001
    int*   cursor = ibase + 100001;                //     50,000
    int*   esrc   = ibase + 150001;                //    800,000
    int*   loc    = ibase + 950001;                //     50,000
    int*   bsum   = ibase + 1000001;               //         64
    int*   boff   = ibase + 1000065;               //         64

    // ---- CSR build ----
    hipMemsetAsync(deg, 0, (size_t)N_NODES * 4, stream);
    count_deg<<<(N_EDGES + 255) / 256, 256, 0, stream>>>(el, deg);
    scan1<<<SCAN_NBLK, 256, 0, stream>>>(deg, loc, bsum);
    scan2<<<1, 64, 0, stream>>>(bsum, boff);
    scan3<<<SCAN_NBLK, 256, 0, stream>>>(deg, loc, boff, ptr, cursor);
    scatter_k<<<(N_EDGES + 255) / 256, 256, 0, stream>>>(el, cursor, esrc);

    // ---- operand packing (fused cast_x + repack_w) ----
    pack_k<<<PACK_NBLK, 256, 0, stream>>>(x, W1, W2, xp, Wp1, Wp2);

    // ---- layer 1 ----
    gemm1<<<dim3(4, N_RT_PAD / 8), 256, 0, stream>>>(xp, Wp1, a1, h1p, s1s, s1d);
    att1<<<(N_NODES + 3) / 4, 256, 0, stream>>>(ptr, esrc, s1s, s1d, h1p, b1, hcatp);

    // ---- layer 2 ----
    gemm2<<<N_RT_PAD / 4, 256, 0, stream>>>(hcatp, Wp2, a2, h2, s2s, s2d);
    att2<<<(N_NODES + 3) / 4, 256, 0, stream>>>(ptr, esrc, s2s, s2d, h2, b2, out);
}

// Round 7
// 550.169 us; speedup vs baseline: 1.1416x; 1.1416x over previous
//
#include <hip/hip_runtime.h>
#include <math.h>

#define N_NODES 50000
#define N_EDGES 800000
#define NFEAT 512
#define NHID 64
#define NHEAD 8
#define NCLASS 40
#define NEG_SLOPE 0.2f

#define N_RT 3125           // 50000/16 row tiles
#define N_RT_PAD 3128       // padded to multiple of 8
#define SCAN_NBLK 49        // ceil(50000/1024)
#define CASTX_NBLK 12512    // N_RT_PAD*1024/256
#define PACK_NBLK (CASTX_NBLK + 140)

typedef __attribute__((ext_vector_type(8))) short short8;
typedef __attribute__((ext_vector_type(4))) short short4v;
typedef __attribute__((ext_vector_type(4))) float f32x4;

__device__ __forceinline__ float bf2f(short s) {
    return __uint_as_float(((unsigned)(unsigned short)s) << 16);
}
__device__ __forceinline__ short f2bf(float f) {
    unsigned u = __float_as_uint(f);
    unsigned r = (u + 0x7FFFu + ((u >> 16) & 1u)) >> 16;
    return (short)(unsigned short)r;
}

// h1 row permutation: slot c' = head*64 + f', f' = (l&15)*4 + ct', head = 2g+(ct>=4)
// orig  c = g*128 + ct*16 + (l&15)

// ---------------- CSR build ----------------

__global__ void count_deg(const int* __restrict__ el, int* __restrict__ deg) {
    int e = blockIdx.x * blockDim.x + threadIdx.x;
    if (e < N_EDGES) atomicAdd(&deg[el[N_EDGES + e]], 1);
}

__global__ __launch_bounds__(256) void scan1(const int* __restrict__ deg,
                                             int* __restrict__ loc,
                                             int* __restrict__ bsum) {
    int tid = threadIdx.x, lane = tid & 63, w = tid >> 6;
    int base = blockIdx.x * 1024 + tid * 4;
    int d0 = (base + 0 < N_NODES) ? deg[base + 0] : 0;
    int d1 = (base + 1 < N_NODES) ? deg[base + 1] : 0;
    int d2 = (base + 2 < N_NODES) ? deg[base + 2] : 0;
    int d3 = (base + 3 < N_NODES) ? deg[base + 3] : 0;
    int s0 = d0, s1 = s0 + d1, s2 = s1 + d2, s3 = s2 + d3;
    int t = s3;
#pragma unroll
    for (int d = 1; d < 64; d <<= 1) {
        int u = __shfl_up(t, d);
        if (lane >= d) t += u;
    }
    __shared__ int wsum[4];
    if (lane == 63) wsum[w] = t;
    __syncthreads();
    int woff = 0;
#pragma unroll
    for (int j = 0; j < 4; ++j) woff += (j < w) ? wsum[j] : 0;
    int excl = woff + t - s3;
    if (base + 0 < N_NODES) loc[base + 0] = excl + s0;
    if (base + 1 < N_NODES) loc[base + 1] = excl + s1;
    if (base + 2 < N_NODES) loc[base + 2] = excl + s2;
    if (base + 3 < N_NODES) loc[base + 3] = excl + s3;
    if (tid == 255) bsum[blockIdx.x] = woff + t;
}

__global__ void scan2(const int* __restrict__ bsum, int* __restrict__ boff) {
    int lane = threadIdx.x;
    int v = (lane < SCAN_NBLK) ? bsum[lane] : 0;
    int t = v;
#pragma unroll
    for (int d = 1; d < 64; d <<= 1) {
        int u = __shfl_up(t, d);
        if (lane >= d) t += u;
    }
    if (lane < SCAN_NBLK) boff[lane] = t - v;
}

__global__ __launch_bounds__(256) void scan3(const int* __restrict__ deg,
                                             const int* __restrict__ loc,
                                             const int* __restrict__ boff,
                                             int* __restrict__ ptr,
                                             int* __restrict__ cursor) {
    int base = blockIdx.x * 1024 + threadIdx.x * 4;
    int off = boff[blockIdx.x];
    if (blockIdx.x == 0 && threadIdx.x == 0) ptr[0] = 0;
#pragma unroll
    for (int k = 0; k < 4; ++k) {
        int i = base + k;
        if (i < N_NODES) {
            int P = off + loc[i];
            ptr[i + 1] = P;
            cursor[i] = P - deg[i];
        }
    }
}

__global__ void scatter_k(const int* __restrict__ el, int* __restrict__ cursor,
                          int* __restrict__ esrc) {
    int e = blockIdx.x * blockDim.x + threadIdx.x;
    if (e >= N_EDGES) return;
    int dst = el[N_EDGES + e];
    int p = atomicAdd(&cursor[dst], 1);
    esrc[p] = el[e];
}

// ---------------- pack: cast x -> A-frag bf16  AND  repack W1/W2 -> B-frag bf16 ----------------
__global__ __launch_bounds__(256) void pack_k(const float* __restrict__ x,
                                              const float* __restrict__ W1,
                                              const float* __restrict__ W2,
                                              short* __restrict__ xp,
                                              short* __restrict__ Wp1,
                                              short* __restrict__ Wp2) {
    if (blockIdx.x < CASTX_NBLK) {
        int t = blockIdx.x * 256 + threadIdx.x;       // < N_RT_PAD*1024
        int l = t & 63, ks = (t >> 6) & 15, rt = t >> 10;
        short8 o;
        if (rt >= N_RT) {
#pragma unroll
            for (int j = 0; j < 8; ++j) o[j] = 0;
        } else {
            int row = rt * 16 + (l & 15);
            int col = ks * 32 + (l >> 4) * 8;
            const float* p = x + (size_t)row * NFEAT + col;
            float4 v0 = *(const float4*)p;
            float4 v1 = *(const float4*)(p + 4);
            o[0] = f2bf(v0.x); o[1] = f2bf(v0.y); o[2] = f2bf(v0.z); o[3] = f2bf(v0.w);
            o[4] = f2bf(v1.x); o[5] = f2bf(v1.y); o[6] = f2bf(v1.z); o[7] = f2bf(v1.w);
        }
        *(short8*)(xp + (size_t)t * 8) = o;
        return;
    }
    int t = (blockIdx.x - CASTX_NBLK) * 256 + threadIdx.x;
    if (t < 32768) {
        int l = t & 63, ct = (t >> 6) & 7, ks = (t >> 9) & 15, g = t >> 13;
        int c = g * 128 + ct * 16 + (l & 15);
        int head = c >> 6, f = c & 63;
        int k0 = ks * 32 + (l >> 4) * 8;
        short8 o;
#pragma unroll
        for (int j = 0; j < 8; ++j)
            o[j] = f2bf(W1[(size_t)head * NFEAT * NHID + (k0 + j) * NHID + f]);
        *(short8*)(Wp1 + (size_t)t * 8) = o;
    } else if (t < 32768 + 3072) {
        int u = t - 32768;
        int l = u & 63;
        int kc = u >> 6;                 // ks*3+ct
        int ct2 = kc % 3, ks = kc / 3;
        int col = ct2 * 16 + (l & 15);
        short8 o;
#pragma unroll
        for (int j = 0; j < 8; ++j) {
            int kp = ks * 32 + (l >> 4) * 8 + j;      // permuted K slot
            int head = kp >> 6, fp = kp & 63;
            int l15 = fp >> 2, ctp = fp & 3;
            int ct = ((head & 1) << 2) | ctp;
            int gg = head >> 1;
            int orig_k = gg * 128 + ct * 16 + l15;
            o[j] = (col < NCLASS) ? f2bf(W2[(size_t)orig_k * NCLASS + col]) : (short)0;
        }
        *(short8*)(Wp2 + (size_t)u * 8) = o;
    }
}

// ---------------- gemm1: waves = colgroups (xp read once/block), 1-deep SW pipeline ----------------
__global__ __launch_bounds__(256, 2) void gemm1(const short* __restrict__ xp,
                                                const short* __restrict__ Wp1,
                                                const float* __restrict__ a1,
                                                short* __restrict__ h1p,
                                                float* __restrict__ s1s,
                                                float* __restrict__ s1d) {
    int w = threadIdx.x >> 6, l = threadIdx.x & 63;
    int g = w;                            // wave = colgroup: all waves share A addresses
    int rt0 = blockIdx.x * 2;
    f32x4 acc[2][8];
#pragma unroll
    for (int i = 0; i < 2; ++i)
#pragma unroll
        for (int ct = 0; ct < 8; ++ct) acc[i][ct] = (f32x4){0.f, 0.f, 0.f, 0.f};

    const short* aP0 = xp + ((size_t)rt0 * 16 * 64 + l) * 8;        // ks stride 512 shorts
    const short* aP1 = xp + ((size_t)(rt0 + 1) * 16 * 64 + l) * 8;
    const short* bP  = Wp1 + (size_t)g * 16 * 4096 + l * 8;         // ks stride 4096, ct stride 512

    short8 a0c = *(const short8*)aP0;
    short8 a1c = *(const short8*)aP1;
    short8 bc[8];
#pragma unroll
    for (int ct = 0; ct < 8; ++ct) bc[ct] = *(const short8*)(bP + ct * 512);

    for (int ks = 0; ks < 16; ++ks) {
        int kn = (ks < 15) ? ks + 1 : ks;
        short8 a0n = *(const short8*)(aP0 + kn * 512);
        short8 a1n = *(const short8*)(aP1 + kn * 512);
        short8 bn[8];
#pragma unroll
        for (int ct = 0; ct < 8; ++ct) bn[ct] = *(const short8*)(bP + kn * 4096 + ct * 512);
#pragma unroll
        for (int ct = 0; ct < 8; ++ct) {
            acc[0][ct] = __builtin_amdgcn_mfma_f32_16x16x32_bf16(a0c, bc[ct], acc[0][ct], 0, 0, 0);
            acc[1][ct] = __builtin_amdgcn_mfma_f32_16x16x32_bf16(a1c, bc[ct], acc[1][ct], 0, 0, 0);
        }
        a0c = a0n; a1c = a1n;
#pragma unroll
        for (int ct = 0; ct < 8; ++ct) bc[ct] = bn[ct];
    }

    float avs[8], avd[8];
#pragma unroll
    for (int ct = 0; ct < 8; ++ct) {
        int head = 2 * g + (ct >> 2);
        int f = (ct & 3) * 16 + (l & 15);
        avs[ct] = a1[head * 128 + f];
        avd[ct] = a1[head * 128 + 64 + f];
    }
    int l15 = l & 15;
    int rbase = (l >> 4) * 4;
#pragma unroll
    for (int i = 0; i < 2; ++i)
#pragma unroll
        for (int r = 0; r < 4; ++r) {
            int row = (rt0 + i) * 16 + rbase + r;
            float ps0 = 0.f, pd0 = 0.f, ps1 = 0.f, pd1 = 0.f;
#pragma unroll
            for (int ct = 0; ct < 4; ++ct) {
                ps0 += acc[i][ct][r] * avs[ct];
                pd0 += acc[i][ct][r] * avd[ct];
            }
#pragma unroll
            for (int ct = 4; ct < 8; ++ct) {
                ps1 += acc[i][ct][r] * avs[ct];
                pd1 += acc[i][ct][r] * avd[ct];
            }
#pragma unroll
            for (int mask = 1; mask < 16; mask <<= 1) {
                ps0 += __shfl_xor(ps0, mask);
                pd0 += __shfl_xor(pd0, mask);
                ps1 += __shfl_xor(ps1, mask);
                pd1 += __shfl_xor(pd1, mask);
            }
            if (row < N_NODES) {
                if (l15 == 0) {
                    s1s[row * 8 + 2 * g]     = ps0;
                    s1d[row * 8 + 2 * g]     = pd0;
                    s1s[row * 8 + 2 * g + 1] = ps1;
                    s1d[row * 8 + 2 * g + 1] = pd1;
                }
                short4v o0, o1;
#pragma unroll
                for (int c = 0; c < 4; ++c) { o0[c] = f2bf(acc[i][c][r]); o1[c] = f2bf(acc[i][4 + c][r]); }
                size_t base = (size_t)row * 512 + g * 128 + l15 * 4;
                *(short4v*)(h1p + base) = o0;
                *(short4v*)(h1p + base + 64) = o1;
            }
        }
}

// ---------------- fused layer-1 attention: wave per dst, ALL heads, 1-deep prefetch ----------------
__global__ __launch_bounds__(256) void att1(const int* __restrict__ ptr,
                                            const int* __restrict__ esrc,
                                            const float* __restrict__ s1s,
                                            const float* __restrict__ s1d,
                                            const short* __restrict__ h1p,
                                            const float* __restrict__ b1,
                                            short* __restrict__ hcatp) {
    int n = blockIdx.x * 4 + (threadIdx.x >> 6);
    int l = threadIdx.x & 63;
    if (n >= N_NODES) return;
    int beg = ptr[n], end = ptr[n + 1];
    int h = l >> 3;                           // permuted: head = l>>3 (slots c' = l*8+j)
    float sd = s1d[n * 8 + h];
    float den = 0.f;
    float acc[8] = {0.f, 0.f, 0.f, 0.f, 0.f, 0.f, 0.f, 0.f};
    if (beg < end) {
        int src = esrc[beg];
        short8 hv = *(const short8*)(h1p + (size_t)src * 512 + l * 8);
        float ss = s1s[src * 8 + h];
        for (int i = beg; i < end; ++i) {
            int ip = (i + 1 < end) ? i + 1 : i;
            int nsrc = esrc[ip];
            short8 nhv = *(const short8*)(h1p + (size_t)nsrc * 512 + l * 8);
            float nss = s1s[nsrc * 8 + h];
            float sc = ss + sd;
            sc = fmaxf(sc, NEG_SLOPE * sc);
            float wgt = __expf(sc);
            den += wgt;
#pragma unroll
            for (int j = 0; j < 8; ++j) acc[j] += wgt * bf2f(hv[j]);
            hv = nhv; ss = nss;
        }
    }
    float rden = 1.f / fmaxf(den, 1e-16f);
    short8 o;
#pragma unroll
    for (int j = 0; j < 8; ++j) {
        // permuted slot c' = l*8+j  ->  orig b1 index = head*64 + (j&3)*16 + (l&7)*2 + (j>>2)
        int forig = (j & 3) * 16 + (l & 7) * 2 + (j >> 2);
        float v = acc[j] * rden + b1[h * 64 + forig];
        v = v > 0.f ? v : (__expf(v) - 1.f);    // ELU
        o[j] = f2bf(v);
    }
    size_t addr = (((size_t)(n >> 4) * 16 + (l >> 2)) * 64 + (l & 3) * 16 + (n & 15)) * 8;
    *(short8*)(hcatp + addr) = o;
}

// ---------------- gemm2: MFMA + fused s2 scores. wave per rowtile ----------------
__global__ __launch_bounds__(256) void gemm2(const short* __restrict__ hcatp,
                                             const short* __restrict__ Wp2,
                                             const float* __restrict__ a2,
                                             short* __restrict__ h2,
                                             float* __restrict__ s2s,
                                             float* __restrict__ s2d) {
    int w = threadIdx.x >> 6, l = threadIdx.x & 63;
    int rt = blockIdx.x * 4 + w;                  // < N_RT_PAD
    f32x4 acc[3];
#pragma unroll
    for (int ct = 0; ct < 3; ++ct) acc[ct] = (f32x4){0.f, 0.f, 0.f, 0.f};
#pragma unroll 2
    for (int ks = 0; ks < 16; ++ks) {
        short8 a = *(const short8*)(hcatp + ((size_t)(rt * 16 + ks) * 64 + l) * 8);
        const short* bp = Wp2 + (size_t)(ks * 3) * 512 + l * 8;
#pragma unroll
        for (int ct = 0; ct < 3; ++ct) {
            short8 b = *(const short8*)(bp + ct * 512);
            acc[ct] = __builtin_amdgcn_mfma_f32_16x16x32_bf16(a, b, acc[ct], 0, 0, 0);
        }
    }
    float ps[4] = {0.f, 0.f, 0.f, 0.f}, pd[4] = {0.f, 0.f, 0.f, 0.f};
    int cl = l & 15, rb = (l >> 4) * 4;
#pragma unroll
    for (int ct = 0; ct < 3; ++ct) {
        int col = ct * 16 + cl;
        if (col < NCLASS) {
#pragma unroll
            for (int r = 0; r < 4; ++r) {
                ps[r] += acc[ct][r] * a2[col];
                pd[r] += acc[ct][r] * a2[NCLASS + col];
                int row = rt * 16 + rb + r;
                if (row < N_NODES) h2[(size_t)row * NCLASS + col] = f2bf(acc[ct][r]);
            }
        }
    }
#pragma unroll
    for (int mask = 1; mask < 16; mask <<= 1)
#pragma unroll
        for (int r = 0; r < 4; ++r) {
            ps[r] += __shfl_xor(ps[r], mask);
            pd[r] += __shfl_xor(pd[r], mask);
        }
    if (cl == 0) {
#pragma unroll
        for (int r = 0; r < 4; ++r) {
            int row = rt * 16 + rb + r;
            if (row < N_NODES) { s2s[row] = ps[r]; s2d[row] = pd[r]; }
        }
    }
}

// ---------------- fused layer-2 attention + log_softmax: wave per dst, 1-deep prefetch ----------------
__global__ __launch_bounds__(256) void att2(const int* __restrict__ ptr,
                                            const int* __restrict__ esrc,
                                            const float* __restrict__ s2s,
                                            const float* __restrict__ s2d,
                                            const short* __restrict__ h2,
                                            const float* __restrict__ b2,
                                            float* __restrict__ out) {
    int n = blockIdx.x * 4 + (threadIdx.x >> 6);
    int l = threadIdx.x & 63;
    if (n >= N_NODES) return;
    int beg = ptr[n], end = ptr[n + 1];
    float sd = s2d[n];
    float den = 0.f, acc = 0.f;
    if (beg < end) {
        int src = esrc[beg];
        float hv = (l < NCLASS) ? bf2f(h2[(size_t)src * NCLASS + l]) : 0.f;
        float ss = s2s[src];
        for (int i = beg; i < end; ++i) {
            int ip = (i + 1 < end) ? i + 1 : i;
            int nsrc = esrc[ip];
            float nhv = (l < NCLASS) ? bf2f(h2[(size_t)nsrc * NCLASS + l]) : 0.f;
            float nss = s2s[nsrc];
            float sc = ss + sd;
            sc = fmaxf(sc, NEG_SLOPE * sc);
            float wgt = __expf(sc);
            den += wgt;
            acc += wgt * hv;
            hv = nhv; ss = nss;
        }
    }
    float v = (l < NCLASS) ? acc / fmaxf(den, 1e-16f) + b2[l] : -INFINITY;
    float mx = v;
#pragma unroll
    for (int o = 32; o; o >>= 1) mx = fmaxf(mx, __shfl_down(mx, o));
    mx = __shfl(mx, 0);
    float ex = (l < NCLASS) ? __expf(v - mx) : 0.f;
    float s = ex;
#pragma unroll
    for (int o = 32; o; o >>= 1) s += __shfl_down(s, o);
    s = __shfl(s, 0);
    float ls = __logf(s);
    if (l < NCLASS) out[(size_t)n * NCLASS + l] = v - mx - ls;
}

// ---------------- launch ----------------

extern "C" void kernel_launch(void* const* d_in, const int* in_sizes, int n_in,
                              void* d_out, int out_size, void* d_ws, size_t ws_size,
                              hipStream_t stream) {
    const float* x  = (const float*)d_in[0];
    const int*   el = (const int*)d_in[1];
    const float* W1 = (const float*)d_in[2];
    const float* a1 = (const float*)d_in[3];
    const float* b1 = (const float*)d_in[4];
    const float* W2 = (const float*)d_in[5];
    const float* a2 = (const float*)d_in[6];
    const float* b2 = (const float*)d_in[7];
    float* out = (float*)d_out;

    short* sbase = (short*)d_ws;
    short* xp    = sbase;                          // 25,624,576
    short* hcatp = sbase + 25624576;               // 25,624,576
    short* h1p   = sbase + 51249152;               // 25,600,000
    short* Wp1   = sbase + 76849152;               //    262,144
    short* Wp2   = sbase + 77111296;               //     24,576
    short* h2    = sbase + 77135872;               //  2,000,000
    float* fbase = (float*)(sbase + 79135872);
    float* s1s   = fbase;                          //    400,000
    float* s1d   = fbase + 400000;                 //    400,000
    float* s2s   = fbase + 800000;                 //     50,000
    float* s2d   = fbase + 850000;                 //     50,000
    int*   ibase = (int*)(fbase + 900000);
    int*   deg    = ibase;                         //     50,000
    int*   ptr    = ibase + 50000;                 //     50,001
    int*   cursor = ibase + 100001;                //     50,000
    int*   esrc   = ibase + 150001;                //    800,000
    int*   loc    = ibase + 950001;                //     50,000
    int*   bsum   = ibase + 1000001;               //         64
    int*   boff   = ibase + 1000065;               //         64

    // ---- CSR build ----
    hipMemsetAsync(deg, 0, (size_t)N_NODES * 4, stream);
    count_deg<<<(N_EDGES + 255) / 256, 256, 0, stream>>>(el, deg);
    scan1<<<SCAN_NBLK, 256, 0, stream>>>(deg, loc, bsum);
    scan2<<<1, 64, 0, stream>>>(bsum, boff);
    scan3<<<SCAN_NBLK, 256, 0, stream>>>(deg, loc, boff, ptr, cursor);
    scatter_k<<<(N_EDGES + 255) / 256, 256, 0, stream>>>(el, cursor, esrc);

    // ---- operand packing ----
    pack_k<<<PACK_NBLK, 256, 0, stream>>>(x, W1, W2, xp, Wp1, Wp2);

    // ---- layer 1 ----
    gemm1<<<N_RT_PAD / 2, 256, 0, stream>>>(xp, Wp1, a1, h1p, s1s, s1d);
    att1<<<(N_NODES + 3) / 4, 256, 0, stream>>>(ptr, esrc, s1s, s1d, h1p, b1, hcatp);

    // ---- layer 2 ----
    gemm2<<<N_RT_PAD / 4, 256, 0, stream>>>(hcatp, Wp2, a2, h2, s2s, s2d);
    att2<<<(N_NODES + 3) / 4, 256, 0, stream>>>(ptr, esrc, s2s, s2d, h2, b2, out);
}

// Round 8
// 545.842 us; speedup vs baseline: 1.1506x; 1.0079x over previous
//
#include <hip/hip_runtime.h>
#include <math.h>

#define N_NODES 50000
#define N_EDGES 800000
#define NFEAT 512
#define NHID 64
#define NHEAD 8
#define NCLASS 40
#define NEG_SLOPE 0.2f

#define N_RT 3125           // 50000/16 row tiles
#define N_RT_PAD 3128       // padded to multiple of 8
#define SCAN_NBLK 49        // ceil(50000/1024)

typedef __attribute__((ext_vector_type(8))) short short8;
typedef __attribute__((ext_vector_type(4))) short short4v;
typedef __attribute__((ext_vector_type(4))) float f32x4;

__device__ __forceinline__ float bf2f(short s) {
    return __uint_as_float(((unsigned)(unsigned short)s) << 16);
}
__device__ __forceinline__ short f2bf(float f) {
    unsigned u = __float_as_uint(f);
    unsigned r = (u + 0x7FFFu + ((u >> 16) & 1u)) >> 16;
    return (short)(unsigned short)r;
}

// h1 row permutation: slot c' = head*64 + f', f' = (l&15)*4 + ct', head = 2g+(ct>=4)
// orig  c = g*128 + ct*16 + (l&15)
// hcat rows are in the same permuted feature order c'; gemm2's A-frag K index
// kp = ks*32 + (lane>>4)*8 + j == c', which pack_w's Wp2 mapping absorbs.

// ---------------- CSR build ----------------

__global__ void count_deg(const int* __restrict__ el, int* __restrict__ deg) {
    int e = blockIdx.x * blockDim.x + threadIdx.x;
    if (e < N_EDGES) atomicAdd(&deg[el[N_EDGES + e]], 1);
}

__global__ __launch_bounds__(256) void scan1(const int* __restrict__ deg,
                                             int* __restrict__ loc,
                                             int* __restrict__ bsum) {
    int tid = threadIdx.x, lane = tid & 63, w = tid >> 6;
    int base = blockIdx.x * 1024 + tid * 4;
    int d0 = (base + 0 < N_NODES) ? deg[base + 0] : 0;
    int d1 = (base + 1 < N_NODES) ? deg[base + 1] : 0;
    int d2 = (base + 2 < N_NODES) ? deg[base + 2] : 0;
    int d3 = (base + 3 < N_NODES) ? deg[base + 3] : 0;
    int s0 = d0, s1 = s0 + d1, s2 = s1 + d2, s3 = s2 + d3;
    int t = s3;
#pragma unroll
    for (int d = 1; d < 64; d <<= 1) {
        int u = __shfl_up(t, d);
        if (lane >= d) t += u;
    }
    __shared__ int wsum[4];
    if (lane == 63) wsum[w] = t;
    __syncthreads();
    int woff = 0;
#pragma unroll
    for (int j = 0; j < 4; ++j) woff += (j < w) ? wsum[j] : 0;
    int excl = woff + t - s3;
    if (base + 0 < N_NODES) loc[base + 0] = excl + s0;
    if (base + 1 < N_NODES) loc[base + 1] = excl + s1;
    if (base + 2 < N_NODES) loc[base + 2] = excl + s2;
    if (base + 3 < N_NODES) loc[base + 3] = excl + s3;
    if (tid == 255) bsum[blockIdx.x] = woff + t;
}

// scan3 with scan2 folded in: each block reduces bsum[0..bid) itself
__global__ __launch_bounds__(256) void scan3(const int* __restrict__ deg,
                                             const int* __restrict__ loc,
                                             const int* __restrict__ bsum,
                                             int* __restrict__ ptr,
                                             int* __restrict__ cursor) {
    __shared__ int sOff;
    if (threadIdx.x < 64) {
        int lane = threadIdx.x;
        int v = (lane < SCAN_NBLK && lane < (int)blockIdx.x) ? bsum[lane] : 0;
#pragma unroll
        for (int m = 1; m < 64; m <<= 1) v += __shfl_xor(v, m);
        if (lane == 0) sOff = v;
    }
    __syncthreads();
    int off = sOff;
    int base = blockIdx.x * 1024 + threadIdx.x * 4;
    if (blockIdx.x == 0 && threadIdx.x == 0) ptr[0] = 0;
#pragma unroll
    for (int k = 0; k < 4; ++k) {
        int i = base + k;
        if (i < N_NODES) {
            int P = off + loc[i];
            ptr[i + 1] = P;
            cursor[i] = P - deg[i];
        }
    }
}

__global__ void scatter_k(const int* __restrict__ el, int* __restrict__ cursor,
                          int* __restrict__ esrc) {
    int e = blockIdx.x * blockDim.x + threadIdx.x;
    if (e >= N_EDGES) return;
    int dst = el[N_EDGES + e];
    int p = atomicAdd(&cursor[dst], 1);
    esrc[p] = el[e];
}

// ---------------- pack W1, W2 into MFMA B-fragment layout (bf16) ----------------
__global__ __launch_bounds__(256) void pack_w(const float* __restrict__ W1,
                                              const float* __restrict__ W2,
                                              short* __restrict__ Wp1,
                                              short* __restrict__ Wp2) {
    int t = blockIdx.x * 256 + threadIdx.x;
    if (t < 32768) {
        int l = t & 63, ct = (t >> 6) & 7, ks = (t >> 9) & 15, g = t >> 13;
        int c = g * 128 + ct * 16 + (l & 15);
        int head = c >> 6, f = c & 63;
        int k0 = ks * 32 + (l >> 4) * 8;
        short8 o;
#pragma unroll
        for (int j = 0; j < 8; ++j)
            o[j] = f2bf(W1[(size_t)head * NFEAT * NHID + (k0 + j) * NHID + f]);
        *(short8*)(Wp1 + (size_t)t * 8) = o;
    } else if (t < 32768 + 3072) {
        int u = t - 32768;
        int l = u & 63;
        int kc = u >> 6;                 // ks*3+ct
        int ct2 = kc % 3, ks = kc / 3;
        int col = ct2 * 16 + (l & 15);
        short8 o;
#pragma unroll
        for (int j = 0; j < 8; ++j) {
            int kp = ks * 32 + (l >> 4) * 8 + j;      // permuted K slot (= c')
            int head = kp >> 6, fp = kp & 63;
            int l15 = fp >> 2, ctp = fp & 3;
            int ct = ((head & 1) << 2) | ctp;
            int gg = head >> 1;
            int orig_k = gg * 128 + ct * 16 + l15;
            o[j] = (col < NCLASS) ? f2bf(W2[(size_t)orig_k * NCLASS + col]) : (short)0;
        }
        *(short8*)(Wp2 + (size_t)u * 8) = o;
    }
}

// ---------------- gemm1: x staged fp32->bf16 A-frags in LDS; waves = colgroups ----------------
__global__ __launch_bounds__(256, 2) void gemm1(const float* __restrict__ x,
                                                const short* __restrict__ Wp1,
                                                const float* __restrict__ a1,
                                                short* __restrict__ h1p,
                                                float* __restrict__ s1s,
                                                float* __restrict__ s1d) {
    __shared__ short As[2 * 16 * 64 * 8];     // 32 KB: 2 rowtiles of A-frags
    int w = threadIdx.x >> 6, l = threadIdx.x & 63;
    int g = w;                                 // wave = colgroup
    int rt0 = blockIdx.x * 2;
    int row0 = rt0 * 16;

    // stage 32 rows x 512 cols of x into LDS in A-frag layout
#pragma unroll
    for (int u = 0; u < 8; ++u) {
        int idx = threadIdx.x + u * 256;       // 0..2047
        int rl = idx >> 6, cg = idx & 63;      // row-local, col-group (8 cols)
        int row = row0 + rl;
        short8 o;
        if (row < N_NODES) {
            const float* p = x + (size_t)row * NFEAT + cg * 8;
            float4 v0 = *(const float4*)p;
            float4 v1 = *(const float4*)(p + 4);
            o[0] = f2bf(v0.x); o[1] = f2bf(v0.y); o[2] = f2bf(v0.z); o[3] = f2bf(v0.w);
            o[4] = f2bf(v1.x); o[5] = f2bf(v1.y); o[6] = f2bf(v1.z); o[7] = f2bf(v1.w);
        } else {
#pragma unroll
            for (int j = 0; j < 8; ++j) o[j] = 0;
        }
        int rtl = rl >> 4, rloc = rl & 15, ks = cg >> 2, sub = cg & 3;
        int lane = rloc + sub * 16;
        *(short8*)(As + (((rtl * 16 + ks) * 64) + lane) * 8) = o;
    }
    __syncthreads();

    f32x4 acc[2][8];
#pragma unroll
    for (int i = 0; i < 2; ++i)
#pragma unroll
        for (int ct = 0; ct < 8; ++ct) acc[i][ct] = (f32x4){0.f, 0.f, 0.f, 0.f};

    const short* bP = Wp1 + (size_t)g * 16 * 4096 + l * 8;   // ks stride 4096, ct stride 512
    short8 bc[8];
#pragma unroll
    for (int ct = 0; ct < 8; ++ct) bc[ct] = *(const short8*)(bP + ct * 512);

    for (int ks = 0; ks < 16; ++ks) {
        int kn = (ks < 15) ? ks + 1 : ks;
        short8 bn[8];
#pragma unroll
        for (int ct = 0; ct < 8; ++ct) bn[ct] = *(const short8*)(bP + kn * 4096 + ct * 512);
        short8 a0 = *(const short8*)(As + ((ks)*64 + l) * 8);
        short8 a1v = *(const short8*)(As + ((16 + ks) * 64 + l) * 8);
#pragma unroll
        for (int ct = 0; ct < 8; ++ct) {
            acc[0][ct] = __builtin_amdgcn_mfma_f32_16x16x32_bf16(a0, bc[ct], acc[0][ct], 0, 0, 0);
            acc[1][ct] = __builtin_amdgcn_mfma_f32_16x16x32_bf16(a1v, bc[ct], acc[1][ct], 0, 0, 0);
        }
#pragma unroll
        for (int ct = 0; ct < 8; ++ct) bc[ct] = bn[ct];
    }

    float avs[8], avd[8];
#pragma unroll
    for (int ct = 0; ct < 8; ++ct) {
        int head = 2 * g + (ct >> 2);
        int f = (ct & 3) * 16 + (l & 15);
        avs[ct] = a1[head * 128 + f];
        avd[ct] = a1[head * 128 + 64 + f];
    }
    int l15 = l & 15;
    int rbase = (l >> 4) * 4;
#pragma unroll
    for (int i = 0; i < 2; ++i)
#pragma unroll
        for (int r = 0; r < 4; ++r) {
            int row = (rt0 + i) * 16 + rbase + r;
            float ps0 = 0.f, pd0 = 0.f, ps1 = 0.f, pd1 = 0.f;
#pragma unroll
            for (int ct = 0; ct < 4; ++ct) {
                ps0 += acc[i][ct][r] * avs[ct];
                pd0 += acc[i][ct][r] * avd[ct];
            }
#pragma unroll
            for (int ct = 4; ct < 8; ++ct) {
                ps1 += acc[i][ct][r] * avs[ct];
                pd1 += acc[i][ct][r] * avd[ct];
            }
#pragma unroll
            for (int mask = 1; mask < 16; mask <<= 1) {
                ps0 += __shfl_xor(ps0, mask);
                pd0 += __shfl_xor(pd0, mask);
                ps1 += __shfl_xor(ps1, mask);
                pd1 += __shfl_xor(pd1, mask);
            }
            if (row < N_NODES) {
                if (l15 == 0) {
                    s1s[row * 8 + 2 * g]     = ps0;
                    s1d[row * 8 + 2 * g]     = pd0;
                    s1s[row * 8 + 2 * g + 1] = ps1;
                    s1d[row * 8 + 2 * g + 1] = pd1;
                }
                short4v o0, o1;
#pragma unroll
                for (int c = 0; c < 4; ++c) { o0[c] = f2bf(acc[i][c][r]); o1[c] = f2bf(acc[i][4 + c][r]); }
                size_t base = (size_t)row * 512 + g * 128 + l15 * 4;
                *(short4v*)(h1p + base) = o0;
                *(short4v*)(h1p + base + 64) = o1;
            }
        }
}

// ---------------- fused layer-1 attention: wave per dst, ALL heads, 1-deep prefetch ----------------
// writes hcat ROW-MAJOR (permuted feature order c' = l*8+j): contiguous 1 KB per node
__global__ __launch_bounds__(256) void att1(const int* __restrict__ ptr,
                                            const int* __restrict__ esrc,
                                            const float* __restrict__ s1s,
                                            const float* __restrict__ s1d,
                                            const short* __restrict__ h1p,
                                            const float* __restrict__ b1,
                                            short* __restrict__ hcat) {
    int n = blockIdx.x * 4 + (threadIdx.x >> 6);
    int l = threadIdx.x & 63;
    if (n >= N_NODES) return;
    int beg = ptr[n], end = ptr[n + 1];
    int h = l >> 3;
    float sd = s1d[n * 8 + h];
    float den = 0.f;
    float acc[8] = {0.f, 0.f, 0.f, 0.f, 0.f, 0.f, 0.f, 0.f};
    if (beg < end) {
        int src = esrc[beg];
        short8 hv = *(const short8*)(h1p + (size_t)src * 512 + l * 8);
        float ss = s1s[src * 8 + h];
        for (int i = beg; i < end; ++i) {
            int ip = (i + 1 < end) ? i + 1 : i;
            int nsrc = esrc[ip];
            short8 nhv = *(const short8*)(h1p + (size_t)nsrc * 512 + l * 8);
            float nss = s1s[nsrc * 8 + h];
            float sc = ss + sd;
            sc = fmaxf(sc, NEG_SLOPE * sc);
            float wgt = __expf(sc);
            den += wgt;
#pragma unroll
            for (int j = 0; j < 8; ++j) acc[j] += wgt * bf2f(hv[j]);
            hv = nhv; ss = nss;
        }
    }
    float rden = 1.f / fmaxf(den, 1e-16f);
    short8 o;
#pragma unroll
    for (int j = 0; j < 8; ++j) {
        // permuted slot c' = l*8+j  ->  orig b1 index = head*64 + (j&3)*16 + (l&7)*2 + (j>>2)
        int forig = (j & 3) * 16 + (l & 7) * 2 + (j >> 2);
        float v = acc[j] * rden + b1[h * 64 + forig];
        v = v > 0.f ? v : (__expf(v) - 1.f);    // ELU
        o[j] = f2bf(v);
    }
    *(short8*)(hcat + (size_t)n * 512 + l * 8) = o;
}

// ---------------- gemm2: row-major hcat A-frags + fused s2 scores ----------------
__global__ __launch_bounds__(256) void gemm2(const short* __restrict__ hcat,
                                             const short* __restrict__ Wp2,
                                             const float* __restrict__ a2,
                                             short* __restrict__ h2,
                                             float* __restrict__ s2s,
                                             float* __restrict__ s2d) {
    int w = threadIdx.x >> 6, l = threadIdx.x & 63;
    int rt = blockIdx.x * 4 + w;                  // < N_RT_PAD
    int arow = rt * 16 + (l & 15);
    const short* aBase = hcat + (size_t)arow * 512 + (l >> 4) * 8;
    f32x4 acc[3];
#pragma unroll
    for (int ct = 0; ct < 3; ++ct) acc[ct] = (f32x4){0.f, 0.f, 0.f, 0.f};
#pragma unroll 2
    for (int ks = 0; ks < 16; ++ks) {
        short8 a = *(const short8*)(aBase + ks * 32);
        const short* bp = Wp2 + (size_t)(ks * 3) * 512 + l * 8;
#pragma unroll
        for (int ct = 0; ct < 3; ++ct) {
            short8 b = *(const short8*)(bp + ct * 512);
            acc[ct] = __builtin_amdgcn_mfma_f32_16x16x32_bf16(a, b, acc[ct], 0, 0, 0);
        }
    }
    float ps[4] = {0.f, 0.f, 0.f, 0.f}, pd[4] = {0.f, 0.f, 0.f, 0.f};
    int cl = l & 15, rb = (l >> 4) * 4;
#pragma unroll
    for (int ct = 0; ct < 3; ++ct) {
        int col = ct * 16 + cl;
        if (col < NCLASS) {
#pragma unroll
            for (int r = 0; r < 4; ++r) {
                ps[r] += acc[ct][r] * a2[col];
                pd[r] += acc[ct][r] * a2[NCLASS + col];
                int row = rt * 16 + rb + r;
                if (row < N_NODES) h2[(size_t)row * NCLASS + col] = f2bf(acc[ct][r]);
            }
        }
    }
#pragma unroll
    for (int mask = 1; mask < 16; mask <<= 1)
#pragma unroll
        for (int r = 0; r < 4; ++r) {
            ps[r] += __shfl_xor(ps[r], mask);
            pd[r] += __shfl_xor(pd[r], mask);
        }
    if (cl == 0) {
#pragma unroll
        for (int r = 0; r < 4; ++r) {
            int row = rt * 16 + rb + r;
            if (row < N_NODES) { s2s[row] = ps[r]; s2d[row] = pd[r]; }
        }
    }
}

// ---------------- fused layer-2 attention + log_softmax: wave per dst, 1-deep prefetch ----------------
__global__ __launch_bounds__(256) void att2(const int* __restrict__ ptr,
                                            const int* __restrict__ esrc,
                                            const float* __restrict__ s2s,
                                            const float* __restrict__ s2d,
                                            const short* __restrict__ h2,
                                            const float* __restrict__ b2,
                                            float* __restrict__ out) {
    int n = blockIdx.x * 4 + (threadIdx.x >> 6);
    int l = threadIdx.x & 63;
    if (n >= N_NODES) return;
    int beg = ptr[n], end = ptr[n + 1];
    float sd = s2d[n];
    float den = 0.f, acc = 0.f;
    if (beg < end) {
        int src = esrc[beg];
        float hv = (l < NCLASS) ? bf2f(h2[(size_t)src * NCLASS + l]) : 0.f;
        float ss = s2s[src];
        for (int i = beg; i < end; ++i) {
            int ip = (i + 1 < end) ? i + 1 : i;
            int nsrc = esrc[ip];
            float nhv = (l < NCLASS) ? bf2f(h2[(size_t)nsrc * NCLASS + l]) : 0.f;
            float nss = s2s[nsrc];
            float sc = ss + sd;
            sc = fmaxf(sc, NEG_SLOPE * sc);
            float wgt = __expf(sc);
            den += wgt;
            acc += wgt * hv;
            hv = nhv; ss = nss;
        }
    }
    float v = (l < NCLASS) ? acc / fmaxf(den, 1e-16f) + b2[l] : -INFINITY;
    float mx = v;
#pragma unroll
    for (int o = 32; o; o >>= 1) mx = fmaxf(mx, __shfl_down(mx, o));
    mx = __shfl(mx, 0);
    float ex = (l < NCLASS) ? __expf(v - mx) : 0.f;
    float s = ex;
#pragma unroll
    for (int o = 32; o; o >>= 1) s += __shfl_down(s, o);
    s = __shfl(s, 0);
    float ls = __logf(s);
    if (l < NCLASS) out[(size_t)n * NCLASS + l] = v - mx - ls;
}

// ---------------- launch ----------------

extern "C" void kernel_launch(void* const* d_in, const int* in_sizes, int n_in,
                              void* d_out, int out_size, void* d_ws, size_t ws_size,
                              hipStream_t stream) {
    const float* x  = (const float*)d_in[0];
    const int*   el = (const int*)d_in[1];
    const float* W1 = (const float*)d_in[2];
    const float* a1 = (const float*)d_in[3];
    const float* b1 = (const float*)d_in[4];
    const float* W2 = (const float*)d_in[5];
    const float* a2 = (const float*)d_in[6];
    const float* b2 = (const float*)d_in[7];
    float* out = (float*)d_out;

    short* sbase = (short*)d_ws;
    short* hcat  = sbase + 25624576;               // 25,624,576 (row-major, permuted cols)
    short* h1p   = sbase + 51249152;               // 25,600,000
    short* Wp1   = sbase + 76849152;               //    262,144
    short* Wp2   = sbase + 77111296;               //     24,576
    short* h2    = sbase + 77135872;               //  2,000,000
    float* fbase = (float*)(sbase + 79135872);
    float* s1s   = fbase;                          //    400,000
    float* s1d   = fbase + 400000;                 //    400,000
    float* s2s   = fbase + 800000;                 //     50,000
    float* s2d   = fbase + 850000;                 //     50,000
    int*   ibase = (int*)(fbase + 900000);
    int*   deg    = ibase;                         //     50,000
    int*   ptr    = ibase + 50000;                 //     50,001
    int*   cursor = ibase + 100001;                //     50,000
    int*   esrc   = ibase + 150001;                //    800,000
    int*   loc    = ibase + 950001;                //     50,000
    int*   bsum   = ibase + 1000001;               //         64

    // ---- CSR build ----
    hipMemsetAsync(deg, 0, (size_t)N_NODES * 4, stream);
    count_deg<<<(N_EDGES + 255) / 256, 256, 0, stream>>>(el, deg);
    scan1<<<SCAN_NBLK, 256, 0, stream>>>(deg, loc, bsum);
    scan3<<<SCAN_NBLK, 256, 0, stream>>>(deg, loc, bsum, ptr, cursor);
    scatter_k<<<(N_EDGES + 255) / 256, 256, 0, stream>>>(el, cursor, esrc);

    // ---- weight packing (x staging now fused into gemm1) ----
    pack_w<<<140, 256, 0, stream>>>(W1, W2, Wp1, Wp2);

    // ---- layer 1 ----
    gemm1<<<N_RT_PAD / 2, 256, 0, stream>>>(x, Wp1, a1, h1p, s1s, s1d);
    att1<<<(N_NODES + 3) / 4, 256, 0, stream>>>(ptr, esrc, s1s, s1d, h1p, b1, hcat);

    // ---- layer 2 ----
    gemm2<<<N_RT_PAD / 4, 256, 0, stream>>>(hcat, Wp2, a2, h2, s2s, s2d);
    att2<<<(N_NODES + 3) / 4, 256, 0, stream>>>(ptr, esrc, s2s, s2d, h2, b2, out);
}